// Round 1
// baseline (755.440 us; speedup 1.0000x reference)
//
#include <hip/hip_runtime.h>
#include <hip/hip_bf16.h>

typedef __attribute__((ext_vector_type(8))) short short8;
typedef __attribute__((ext_vector_type(8))) __bf16 bf16x8;
typedef __attribute__((ext_vector_type(4))) float f32x4;

#define NN 100000
#define HD 384
#define K1T 22   // GEMM1 k-tiles: 704/32 (700 padded with zeros)
#define K2T 24   // GEMM2 k-tiles: 768/32 ([h1 | he])

// d_ws byte offsets
#define OFF_B1 0         // W1g bf16, pre-swizzled frag order: 24*22*64*8 shorts = 540672 B
#define OFF_B2 540672    // [W2g;W2e] bf16 frag order: 24*24*64*8 shorts = 589824 B
#define OFF_T  1130496   // T[6][384] f32 = W1e[t]+b1e
#define OFF_V  1139712   // V[384] f32 = W1e[6]
#define OFF_BI 1141248   // bias2[384] f32 = b2g+b2e

union Frag { short s[8]; bf16x8 v; };

__device__ __forceinline__ short f2bf(float f) {
  unsigned u = __builtin_bit_cast(unsigned, f);
  u += 0x7FFF + ((u >> 16) & 1);   // RNE
  return (short)(u >> 16);
}

__global__ void prep_kernel(const float* __restrict__ W1g, const float* __restrict__ b1g,
                            const float* __restrict__ W2g, const float* __restrict__ b2g,
                            const float* __restrict__ W1e, const float* __restrict__ b1e,
                            const float* __restrict__ W2e, const float* __restrict__ b2e,
                            char* __restrict__ ws) {
  int t = blockIdx.x * 256 + threadIdx.x;
  short* B1 = (short*)(ws + OFF_B1);
  short* B2 = (short*)(ws + OFF_B2);
  float* Tt = (float*)(ws + OFF_T);
  float* Vt = (float*)(ws + OFF_V);
  float* Bi = (float*)(ws + OFF_BI);
  if (t < 33792) {                       // B1: (nt,kt,lane) -> 8 shorts
    int lane = t & 63, rest = t >> 6;
    int kt = rest % K1T, nt = rest / K1T;
    int col = nt * 16 + (lane & 15);
    int kb = kt * 32 + (lane >> 4) * 8;
    short8 v;
#pragma unroll
    for (int i = 0; i < 8; ++i) {
      int k = kb + i;
      v[i] = (k < 700) ? f2bf(W1g[k * 384 + col]) : (short)0;
    }
    *(short8*)(B1 + (size_t)t * 8) = v;
  } else if (t < 70656) {                // B2: (nt,kt2,lane) -> 8 shorts
    int t2 = t - 33792;
    int lane = t2 & 63, rest = t2 >> 6;
    int kt = rest % K2T, nt = rest / K2T;
    int col = nt * 16 + (lane & 15);
    int kb = kt * 32 + (lane >> 4) * 8;
    short8 v;
#pragma unroll
    for (int i = 0; i < 8; ++i) {
      int k = kb + i;
      v[i] = (k < 384) ? f2bf(W2g[k * 384 + col]) : f2bf(W2e[(k - 384) * 384 + col]);
    }
    *(short8*)(B2 + (size_t)t2 * 8) = v;
  } else if (t < 73728) {                // tables
    int r = t - 70656;
    int which = r / 384, c = r % 384;
    if (which < 6)       Tt[r] = W1e[which * 384 + c] + b1e[c];
    else if (which == 6) Vt[c] = W1e[6 * 384 + c];
    else                 Bi[c] = b2g[c] + b2e[c];
  }
}

__global__ __launch_bounds__(256, 2) void face_embed_kernel(
    const float* __restrict__ x1, const float* __restrict__ isf1,
    const int* __restrict__ et1, const float* __restrict__ ar1,
    const float* __restrict__ x2, const float* __restrict__ isf2,
    const int* __restrict__ et2, const float* __restrict__ ar2,
    const float* __restrict__ b1g, const char* __restrict__ ws,
    float* __restrict__ out) {
  const int graph = blockIdx.y;
  const float* x   = graph ? x2 : x1;
  const float* isf = graph ? isf2 : isf1;
  const int*   et  = graph ? et2 : et1;
  const float* ar  = graph ? ar2 : ar1;
  float* o = out + (size_t)graph * NN * HD;

  const bf16x8* B1 = (const bf16x8*)(ws + OFF_B1);
  const bf16x8* B2 = (const bf16x8*)(ws + OFF_B2);
  const float* Tg  = (const float*)(ws + OFF_T);
  const float* Vg  = (const float*)(ws + OFF_V);
  const float* Big = (const float*)(ws + OFF_BI);

  __shared__ short h1s[64 * 384];   // bf16 [64][384], XOR-swizzled bytes
  __shared__ float Ts[6 * 384];
  __shared__ float Vs[384];
  __shared__ float b1s[384];
  __shared__ float b2s[384];

  const int tid = threadIdx.x;
  for (int i = tid; i < 6 * 384; i += 256) Ts[i] = Tg[i];
  for (int i = tid; i < 384; i += 256) { Vs[i] = Vg[i]; b1s[i] = b1g[i]; b2s[i] = Big[i]; }

  const int wid = tid >> 6, lane = tid & 63;
  const int mg = wid >> 1, ng = wid & 1;
  const int lr = lane & 15, g = lane >> 4;
  const int row0 = blockIdx.x * 64;

  // ---------------- GEMM1: h1 = x @ W1g ----------------
  f32x4 acc[2][12] = {};
  {
    int arow[2];
#pragma unroll
    for (int m = 0; m < 2; ++m) {
      int r = row0 + (2 * mg + m) * 16 + lr;
      arow[m] = r < NN ? r : NN - 1;
    }
    for (int kt = 0; kt < K1T; ++kt) {
      int k0 = kt * 32 + g * 8;
      Frag a[2];
#pragma unroll
      for (int m = 0; m < 2; ++m) {
        const float* xp = x + (size_t)arow[m] * 700 + k0;
        float v[8];
        if (kt < 21) {
          f32x4 lo = *(const f32x4*)xp;
          f32x4 hi = *(const f32x4*)(xp + 4);
          v[0] = lo[0]; v[1] = lo[1]; v[2] = lo[2]; v[3] = lo[3];
          v[4] = hi[0]; v[5] = hi[1]; v[6] = hi[2]; v[7] = hi[3];
        } else {
#pragma unroll
          for (int i = 0; i < 8; ++i) v[i] = (k0 + i < 700) ? xp[i] : 0.f;
        }
#pragma unroll
        for (int i = 0; i < 8; ++i) a[m].s[i] = f2bf(v[i]);
      }
#pragma unroll
      for (int n = 0; n < 12; ++n) {
        bf16x8 b = B1[((ng * 12 + n) * K1T + kt) * 64 + lane];
#pragma unroll
        for (int m = 0; m < 2; ++m)
          acc[m][n] = __builtin_amdgcn_mfma_f32_16x16x32_bf16(a[m].v, b, acc[m][n], 0, 0, 0);
      }
    }
  }

  __syncthreads();   // tables staged; h1s free to write

  // ---------------- h1 = elu(acc + b1g) -> LDS bf16 (swizzled) ----------------
#pragma unroll
  for (int m = 0; m < 2; ++m)
#pragma unroll
    for (int n = 0; n < 12; ++n) {
      int col = (ng * 12 + n) * 16 + lr;
      float bias = b1s[col];
#pragma unroll
      for (int r2 = 0; r2 < 4; ++r2) {
        int row = (2 * mg + m) * 16 + 4 * g + r2;
        float hv = acc[m][n][r2] + bias;
        hv = hv > 0.f ? hv : __expf(hv) - 1.f;
        int byte = (row * 768 + col * 2) ^ ((row & 7) << 4);
        *(short*)((char*)h1s + byte) = f2bf(hv);
      }
    }
  __syncthreads();

  // entity-branch per-node params (A rows for this wave)
  int nde[2]; float nda[2];
#pragma unroll
  for (int m = 0; m < 2; ++m) {
    int r = row0 + (2 * mg + m) * 16 + lr;
    r = r < NN ? r : NN - 1;
    nde[m] = et[r]; nda[m] = ar[r];
  }

  // ---------------- GEMM2: out = [h1|he] @ [W2g;W2e] ----------------
  f32x4 acc2[2][12] = {};
  for (int kt = 0; kt < K2T; ++kt) {
    Frag a[2];
    if (kt < 12) {
#pragma unroll
      for (int m = 0; m < 2; ++m) {
        int row = (2 * mg + m) * 16 + lr;
        int byte = (row * 768 + (kt * 32 + g * 8) * 2) ^ ((row & 7) << 4);
        a[m].v = *(const bf16x8*)((const char*)h1s + byte);
      }
    } else {
      int c0 = (kt - 12) * 32 + g * 8;
#pragma unroll
      for (int m = 0; m < 2; ++m) {
#pragma unroll
        for (int i = 0; i < 8; ++i) {
          float t = Ts[nde[m] * 384 + c0 + i] + nda[m] * Vs[c0 + i];
          t = t > 0.f ? t : __expf(t) - 1.f;
          a[m].s[i] = f2bf(t);
        }
      }
    }
#pragma unroll
    for (int n = 0; n < 12; ++n) {
      bf16x8 b = B2[((ng * 12 + n) * K2T + kt) * 64 + lane];
#pragma unroll
      for (int m = 0; m < 2; ++m)
        acc2[m][n] = __builtin_amdgcn_mfma_f32_16x16x32_bf16(a[m].v, b, acc2[m][n], 0, 0, 0);
    }
  }

  // ---------------- epilogue: +bias2, mask, store f32 ----------------
#pragma unroll
  for (int m = 0; m < 2; ++m) {
#pragma unroll
    for (int r2 = 0; r2 < 4; ++r2) {
      int node = row0 + (2 * mg + m) * 16 + 4 * g + r2;
      if (node < NN) {
        bool face = isf[node] > 0.5f;
#pragma unroll
        for (int n = 0; n < 12; ++n) {
          int col = (ng * 12 + n) * 16 + lr;
          float val = face ? acc2[m][n][r2] + b2s[col] : 0.f;
          o[(size_t)node * HD + col] = val;
        }
      }
    }
  }
}

extern "C" void kernel_launch(void* const* d_in, const int* in_sizes, int n_in,
                              void* d_out, int out_size, void* d_ws, size_t ws_size,
                              hipStream_t stream) {
  (void)n_in; (void)out_size; (void)ws_size;
  const float* x1  = (const float*)d_in[0];
  const float* is1 = (const float*)d_in[1];
  const int*   et1 = (const int*)d_in[2];
  const float* ar1 = (const float*)d_in[3];
  const float* x2  = (const float*)d_in[4];
  const float* is2 = (const float*)d_in[5];
  const int*   et2 = (const int*)d_in[6];
  const float* ar2 = (const float*)d_in[7];
  const float* W1g = (const float*)d_in[8];
  const float* b1g = (const float*)d_in[9];
  const float* W2g = (const float*)d_in[10];
  const float* b2g = (const float*)d_in[11];
  const float* W1e = (const float*)d_in[12];
  const float* b1e = (const float*)d_in[13];
  const float* W2e = (const float*)d_in[14];
  const float* b2e = (const float*)d_in[15];
  float* out = (float*)d_out;
  char* ws = (char*)d_ws;

  prep_kernel<<<dim3(288), dim3(256), 0, stream>>>(W1g, b1g, W2g, b2g, W1e, b1e, W2e, b2e, ws);

  int n = in_sizes[1];                 // 100000 nodes
  dim3 grid((n + 63) / 64, 2);
  face_embed_kernel<<<grid, dim3(256), 0, stream>>>(
      x1, is1, et1, ar1, x2, is2, et2, ar2, b1g, ws, out);
}

// Round 2
// 620.402 us; speedup vs baseline: 1.2177x; 1.2177x over previous
//
#include <hip/hip_runtime.h>
#include <hip/hip_bf16.h>

typedef __attribute__((ext_vector_type(8))) short short8;
typedef __attribute__((ext_vector_type(8))) __bf16 bf16x8;
typedef __attribute__((ext_vector_type(4))) float f32x4;

#define NN 100000
#define HD 384
#define K1T 22   // GEMM1 k-tiles: 704/32 (700 padded with zeros)
#define K2T 24   // GEMM2 k-tiles: 768/32 ([h1 | he])

// d_ws byte offsets
#define OFF_B1 0         // W1g bf16, pre-swizzled frag order: 24*22*64*8 shorts = 540672 B
#define OFF_B2 540672    // [W2g;W2e] bf16 frag order: 24*24*64*8 shorts = 589824 B
#define OFF_T  1130496   // T[6][384] f32 = W1e[t]+b1e
#define OFF_V  1139712   // V[384] f32 = W1e[6]
#define OFF_BI 1141248   // bias2[384] f32 = b2g+b2e

union Frag { short s[8]; bf16x8 v; };

__device__ __forceinline__ short f2bf(float f) {
  union { __bf16 h; short s; } u;
  u.h = (__bf16)f;                 // native cvt (RNE) on gfx950
  return u.s;
}

__device__ __forceinline__ float elu(float v) {
  return v > 0.f ? v : __expf(v) - 1.f;
}

__global__ void prep_kernel(const float* __restrict__ W1g, const float* __restrict__ b1g,
                            const float* __restrict__ W2g, const float* __restrict__ b2g,
                            const float* __restrict__ W1e, const float* __restrict__ b1e,
                            const float* __restrict__ W2e, const float* __restrict__ b2e,
                            char* __restrict__ ws) {
  int t = blockIdx.x * 256 + threadIdx.x;
  short* B1 = (short*)(ws + OFF_B1);
  short* B2 = (short*)(ws + OFF_B2);
  float* Tt = (float*)(ws + OFF_T);
  float* Vt = (float*)(ws + OFF_V);
  float* Bi = (float*)(ws + OFF_BI);
  if (t < 33792) {                       // B1: (nt,kt,lane) -> 8 shorts
    int lane = t & 63, rest = t >> 6;
    int kt = rest % K1T, nt = rest / K1T;
    int col = nt * 16 + (lane & 15);
    int kb = kt * 32 + (lane >> 4) * 8;
    short8 v;
#pragma unroll
    for (int i = 0; i < 8; ++i) {
      int k = kb + i;
      v[i] = (k < 700) ? f2bf(W1g[k * 384 + col]) : (short)0;
    }
    *(short8*)(B1 + (size_t)t * 8) = v;
  } else if (t < 70656) {                // B2: (nt,kt2,lane) -> 8 shorts
    int t2 = t - 33792;
    int lane = t2 & 63, rest = t2 >> 6;
    int kt = rest % K2T, nt = rest / K2T;
    int col = nt * 16 + (lane & 15);
    int kb = kt * 32 + (lane >> 4) * 8;
    short8 v;
#pragma unroll
    for (int i = 0; i < 8; ++i) {
      int k = kb + i;
      v[i] = (k < 384) ? f2bf(W2g[k * 384 + col]) : f2bf(W2e[(k - 384) * 384 + col]);
    }
    *(short8*)(B2 + (size_t)t2 * 8) = v;
  } else if (t < 73728) {                // tables
    int r = t - 70656;
    int which = r / 384, c = r % 384;
    if (which < 6)       Tt[r] = W1e[which * 384 + c] + b1e[c];
    else if (which == 6) Vt[c] = W1e[6 * 384 + c];
    else                 Bi[c] = b2g[c] + b2e[c];
  }
}

// 32 rows/block, 4 waves: each wave = 32 rows x 96 cols (6 n-tiles), acc[2][6].
// LDS = h1 tile only (24.6 KB) -> 4 blocks/CU.
__global__ __launch_bounds__(256, 4) void face_embed_kernel(
    const float* __restrict__ x1, const float* __restrict__ isf1,
    const int* __restrict__ et1, const float* __restrict__ ar1,
    const float* __restrict__ x2, const float* __restrict__ isf2,
    const int* __restrict__ et2, const float* __restrict__ ar2,
    const float* __restrict__ b1g, const char* __restrict__ ws,
    float* __restrict__ out) {
  const int graph = blockIdx.y;
  const float* x   = graph ? x2 : x1;
  const float* isf = graph ? isf2 : isf1;
  const int*   et  = graph ? et2 : et1;
  const float* ar  = graph ? ar2 : ar1;
  float* o = out + (size_t)graph * NN * HD;

  const bf16x8* B1 = (const bf16x8*)(ws + OFF_B1);
  const bf16x8* B2 = (const bf16x8*)(ws + OFF_B2);
  const float* Tg  = (const float*)(ws + OFF_T);
  const float* Vg  = (const float*)(ws + OFF_V);
  const float* Big = (const float*)(ws + OFF_BI);

  __shared__ short h1s[32 * 384];   // bf16 [32][384], XOR-swizzled bytes

  const int tid = threadIdx.x;
  const int wid = tid >> 6, lane = tid & 63;
  const int lr = lane & 15, g = lane >> 4;
  const int row0 = blockIdx.x * 32;

  // per-lane bias preloads (6 cols per wave-lane)
  float b1c[6], b2c[6];
#pragma unroll
  for (int n = 0; n < 6; ++n) {
    int col = (wid * 6 + n) * 16 + lr;
    b1c[n] = b1g[col];
    b2c[n] = Big[col];
  }

  // ---------------- GEMM1: h1 = x @ W1g ----------------
  f32x4 acc[2][6] = {};
  {
    const float* xp0 = x + (size_t)(row0 + lr) * 700;
    const float* xp1 = x + (size_t)(row0 + 16 + lr) * 700;
    for (int kt = 0; kt < K1T; ++kt) {
      int k0 = kt * 32 + g * 8;
      Frag a[2];
#pragma unroll
      for (int m = 0; m < 2; ++m) {
        const float* xp = (m ? xp1 : xp0) + k0;
        if (kt < 21 || g < 3) {
          f32x4 lo = *(const f32x4*)xp;
          f32x4 hi = *(const f32x4*)(xp + 4);
#pragma unroll
          for (int i = 0; i < 4; ++i) { a[m].s[i] = f2bf(lo[i]); a[m].s[4 + i] = f2bf(hi[i]); }
        } else {  // kt==21, g==3: cols 696..703, only 696..699 valid (B1 is 0 for k>=700)
#pragma unroll
          for (int i = 0; i < 8; ++i) a[m].s[i] = (k0 + i < 700) ? f2bf(xp[i]) : (short)0;
        }
      }
#pragma unroll
      for (int n = 0; n < 6; ++n) {
        bf16x8 b = B1[((wid * 6 + n) * K1T + kt) * 64 + lane];
#pragma unroll
        for (int m = 0; m < 2; ++m)
          acc[m][n] = __builtin_amdgcn_mfma_f32_16x16x32_bf16(a[m].v, b, acc[m][n], 0, 0, 0);
      }
    }
  }

  // ---------------- h1 = elu(acc + b1g) -> LDS bf16 (swizzled) ----------------
#pragma unroll
  for (int m = 0; m < 2; ++m)
#pragma unroll
    for (int n = 0; n < 6; ++n) {
      int col = (wid * 6 + n) * 16 + lr;
#pragma unroll
      for (int r2 = 0; r2 < 4; ++r2) {
        int row = m * 16 + 4 * g + r2;
        float hv = elu(acc[m][n][r2] + b1c[n]);
        int byte = (row * 768 + col * 2) ^ ((row & 15) << 4);
        *(short*)((char*)h1s + byte) = f2bf(hv);
      }
    }
  __syncthreads();

  // entity-branch per-node params (A rows for this wave)
  int nde[2]; float nda[2];
#pragma unroll
  for (int m = 0; m < 2; ++m) {
    int r = row0 + m * 16 + lr;
    nde[m] = et[r]; nda[m] = ar[r];
  }

  // ---------------- GEMM2: out = [h1|he] @ [W2g;W2e] ----------------
  f32x4 acc2[2][6] = {};
  for (int kt = 0; kt < K2T; ++kt) {
    Frag a[2];
    if (kt < 12) {
#pragma unroll
      for (int m = 0; m < 2; ++m) {
        int row = m * 16 + lr;
        int byte = (row * 768 + (kt * 32 + g * 8) * 2) ^ ((row & 15) << 4);
        a[m].v = *(const bf16x8*)((const char*)h1s + byte);
      }
    } else {
      int c0 = (kt - 12) * 32 + g * 8;
#pragma unroll
      for (int m = 0; m < 2; ++m) {
        const float* Tp = Tg + nde[m] * 384 + c0;
        const float* Vp = Vg + c0;
#pragma unroll
        for (int i = 0; i < 8; ++i)
          a[m].s[i] = f2bf(elu(Tp[i] + nda[m] * Vp[i]));
      }
    }
#pragma unroll
    for (int n = 0; n < 6; ++n) {
      bf16x8 b = B2[((wid * 6 + n) * K2T + kt) * 64 + lane];
#pragma unroll
      for (int m = 0; m < 2; ++m)
        acc2[m][n] = __builtin_amdgcn_mfma_f32_16x16x32_bf16(a[m].v, b, acc2[m][n], 0, 0, 0);
    }
  }

  // ---------------- epilogue: +bias2, mask, store f32 ----------------
#pragma unroll
  for (int m = 0; m < 2; ++m) {
#pragma unroll
    for (int r2 = 0; r2 < 4; ++r2) {
      int node = row0 + m * 16 + 4 * g + r2;
      bool face = isf[node] > 0.5f;
#pragma unroll
      for (int n = 0; n < 6; ++n) {
        int col = (wid * 6 + n) * 16 + lr;
        float val = face ? acc2[m][n][r2] + b2c[n] : 0.f;
        o[(size_t)node * HD + col] = val;
      }
    }
  }
}

extern "C" void kernel_launch(void* const* d_in, const int* in_sizes, int n_in,
                              void* d_out, int out_size, void* d_ws, size_t ws_size,
                              hipStream_t stream) {
  (void)n_in; (void)out_size; (void)ws_size;
  const float* x1  = (const float*)d_in[0];
  const float* is1 = (const float*)d_in[1];
  const int*   et1 = (const int*)d_in[2];
  const float* ar1 = (const float*)d_in[3];
  const float* x2  = (const float*)d_in[4];
  const float* is2 = (const float*)d_in[5];
  const int*   et2 = (const int*)d_in[6];
  const float* ar2 = (const float*)d_in[7];
  const float* W1g = (const float*)d_in[8];
  const float* b1g = (const float*)d_in[9];
  const float* W2g = (const float*)d_in[10];
  const float* b2g = (const float*)d_in[11];
  const float* W1e = (const float*)d_in[12];
  const float* b1e = (const float*)d_in[13];
  const float* W2e = (const float*)d_in[14];
  const float* b2e = (const float*)d_in[15];
  float* out = (float*)d_out;
  char* ws = (char*)d_ws;

  prep_kernel<<<dim3(288), dim3(256), 0, stream>>>(W1g, b1g, W2g, b2g, W1e, b1e, W2e, b2e, ws);

  int n = in_sizes[1];                 // 100000 nodes
  dim3 grid(n / 32, 2);
  face_embed_kernel<<<grid, dim3(256), 0, stream>>>(
      x1, is1, et1, ar1, x2, is2, et2, ar2, b1g, ws, out);
}

// Round 4
// 371.103 us; speedup vs baseline: 2.0357x; 1.6718x over previous
//
#include <hip/hip_runtime.h>
#include <hip/hip_bf16.h>

typedef __attribute__((ext_vector_type(8))) short short8;
typedef __attribute__((ext_vector_type(4))) short svec4;
typedef __attribute__((ext_vector_type(8))) __bf16 bf16x8;
typedef __attribute__((ext_vector_type(4))) float f32x4;

#define NN 100000
#define HD 384
#define K1T 22   // GEMM1 k-tiles: 704/32 (700 padded with zeros)
#define K2T 24   // GEMM2 k-tiles: 768/32 ([h1 | he])
#define NBLK 98  // ceil(NN/1024) for count/compact

// d_ws byte offsets
#define OFF_B1  0         // W1g bf16 frag order: 24*22*64*8 shorts = 540672 B
#define OFF_B2  540672    // [W2g;W2e] bf16 frag order: 589824 B
#define OFF_T   1130496   // T[6][384] f32 = W1e[t]+b1e
#define OFF_V   1139712   // V[384] f32 = W1e[6]
#define OFF_BI  1141248   // bias2[384] f32 = b2g+b2e
#define OFF_IDX 1142784   // int idx[2][NN]: faces [0,totF), non-faces [totF,NN)
#define OFF_CNT 1942784   // int cnt[2][NBLK]
#define OFF_OFFS 1943568  // int offs[2][NBLK]
#define OFF_TOT 1944352   // int tot[2]

union Frag { short s[8]; bf16x8 v; };

__device__ __forceinline__ short f2bf(float f) {
  union { __bf16 h; short s; } u;
  u.h = (__bf16)f;                 // native cvt (RNE) on gfx950
  return u.s;
}

__device__ __forceinline__ float elu(float v) {
  return v > 0.f ? v : __expf(v) - 1.f;
}

__global__ void prep_kernel(const float* __restrict__ W1g, const float* __restrict__ b1g,
                            const float* __restrict__ W2g, const float* __restrict__ b2g,
                            const float* __restrict__ W1e, const float* __restrict__ b1e,
                            const float* __restrict__ W2e, const float* __restrict__ b2e,
                            char* __restrict__ ws) {
  int t = blockIdx.x * 256 + threadIdx.x;
  short* B1 = (short*)(ws + OFF_B1);
  short* B2 = (short*)(ws + OFF_B2);
  float* Tt = (float*)(ws + OFF_T);
  float* Vt = (float*)(ws + OFF_V);
  float* Bi = (float*)(ws + OFF_BI);
  if (t < 33792) {                       // B1: (nt,kt,lane) -> 8 shorts
    int lane = t & 63, rest = t >> 6;
    int kt = rest % K1T, nt = rest / K1T;
    int col = nt * 16 + (lane & 15);
    int kb = kt * 32 + (lane >> 4) * 8;
    short8 v;
#pragma unroll
    for (int i = 0; i < 8; ++i) {
      int k = kb + i;
      v[i] = (k < 700) ? f2bf(W1g[k * 384 + col]) : (short)0;
    }
    *(short8*)(B1 + (size_t)t * 8) = v;
  } else if (t < 70656) {                // B2
    int t2 = t - 33792;
    int lane = t2 & 63, rest = t2 >> 6;
    int kt = rest % K2T, nt = rest / K2T;
    int col = nt * 16 + (lane & 15);
    int kb = kt * 32 + (lane >> 4) * 8;
    short8 v;
#pragma unroll
    for (int i = 0; i < 8; ++i) {
      int k = kb + i;
      v[i] = (k < 384) ? f2bf(W2g[k * 384 + col]) : f2bf(W2e[(k - 384) * 384 + col]);
    }
    *(short8*)(B2 + (size_t)t2 * 8) = v;
  } else if (t < 73728) {                // tables
    int r = t - 70656;
    int which = r / 384, c = r % 384;
    if (which < 6)       Tt[r] = W1e[which * 384 + c] + b1e[c];
    else if (which == 6) Vt[c] = W1e[6 * 384 + c];
    else                 Bi[c] = b2g[c] + b2e[c];
  }
}

__global__ void count_kernel(const float* __restrict__ isf1, const float* __restrict__ isf2,
                             char* __restrict__ ws) {
  int g = blockIdx.y;
  const float* isf = g ? isf2 : isf1;
  int i = blockIdx.x * 1024 + threadIdx.x;
  bool face = (i < NN) && (isf[i] > 0.5f);
  unsigned long long b = __ballot(face);
  __shared__ int wc[16];
  int lane = threadIdx.x & 63, wid = threadIdx.x >> 6;
  if (lane == 0) wc[wid] = __popcll(b);
  __syncthreads();
  if (threadIdx.x == 0) {
    int s = 0;
#pragma unroll
    for (int w = 0; w < 16; ++w) s += wc[w];
    ((int*)(ws + OFF_CNT))[g * NBLK + blockIdx.x] = s;
  }
}

__global__ void scan_kernel(char* __restrict__ ws) {
  int t = threadIdx.x;
  if (t < 2) {
    const int* cnt = (const int*)(ws + OFF_CNT) + t * NBLK;
    int* offs = (int*)(ws + OFF_OFFS) + t * NBLK;
    int* tot = (int*)(ws + OFF_TOT);
    int run = 0;
    for (int b = 0; b < NBLK; ++b) { offs[b] = run; run += cnt[b]; }
    tot[t] = run;
  }
}

__global__ void compact_kernel(const float* __restrict__ isf1, const float* __restrict__ isf2,
                               char* __restrict__ ws) {
  int g = blockIdx.y;
  const float* isf = g ? isf2 : isf1;
  const int* offs = (const int*)(ws + OFF_OFFS) + g * NBLK;
  int totF = ((const int*)(ws + OFF_TOT))[g];
  int* idx = (int*)(ws + OFF_IDX) + g * NN;
  int bx = blockIdx.x;
  int i = bx * 1024 + threadIdx.x;
  bool valid = i < NN;
  bool face = valid && (isf[i] > 0.5f);
  unsigned long long bf = __ballot(face);
  unsigned long long bv = __ballot(valid);
  int lane = threadIdx.x & 63, wid = threadIdx.x >> 6;
  __shared__ int wF[16], wV[16];
  if (lane == 0) { wF[wid] = __popcll(bf); wV[wid] = __popcll(bv); }
  __syncthreads();
  int baseF = 0, baseV = 0;
  for (int w = 0; w < wid; ++w) { baseF += wF[w]; baseV += wV[w]; }
  unsigned long long lmask = (1ull << lane) - 1ull;
  int pF = __popcll(bf & lmask);
  int pV = __popcll(bv & lmask);
  if (face) {
    idx[offs[bx] + baseF + pF] = i;
  } else if (valid) {
    int nfBefore = bx * 1024 - offs[bx];          // valid non-faces before this block
    int nfIn = (baseV + pV) - (baseF + pF);       // non-faces before me in block
    idx[totF + nfBefore + nfIn] = i;
  }
}

// 32 gathered face rows/block, 4 waves: each wave = 32 rows x 96 cols, acc[2][6].
// LDS = A-tile bf16 [32][704] swizzled (45 KB), reused for h1 tile. 3 blocks/CU.
// Trailing blocks write zeros for non-face rows.
__global__ __launch_bounds__(256, 3) void face_embed_kernel(
    const float* __restrict__ x1, const int* __restrict__ et1, const float* __restrict__ ar1,
    const float* __restrict__ x2, const int* __restrict__ et2, const float* __restrict__ ar2,
    const float* __restrict__ b1g, const char* __restrict__ ws,
    float* __restrict__ out) {
  const int g = blockIdx.y;
  const float* x = g ? x2 : x1;
  const int* et  = g ? et2 : et1;
  const float* ar = g ? ar2 : ar1;
  float* o = out + (size_t)g * NN * HD;
  const int* idx = (const int*)(ws + OFF_IDX) + g * NN;
  const int totF = ((const int*)(ws + OFF_TOT))[g];
  const int nFB = (totF + 31) >> 5;
  const int bx = blockIdx.x;
  const int tid = threadIdx.x;

  if (bx >= nFB) {                       // ---- zero path (non-face rows) ----
    int totN = NN - totF;
    int base = (bx - nFB) * 32;
    if (base >= totN) return;
    const int* idxN = idx + totF;
    f32x4 z = {0.f, 0.f, 0.f, 0.f};
#pragma unroll
    for (int it = 0; it < 12; ++it) {
      int c = tid + it * 256;            // 32 rows x 96 f32x4 chunks = 3072
      int r = c / 96, cc = c % 96;
      if (base + r < totN) {
        int node = idxN[base + r];
        *(f32x4*)(o + (size_t)node * HD + cc * 4) = z;
      }
    }
    return;
  }

  // ---- GEMM path on gathered face rows ----
  __shared__ short As[32 * 704];         // 45056 B swizzled A-tile; reused for h1
  __shared__ int sN[32];
  short* h1s = As;

  const bf16x8* B1 = (const bf16x8*)(ws + OFF_B1);
  const bf16x8* B2 = (const bf16x8*)(ws + OFF_B2);
  const float* Tg  = (const float*)(ws + OFF_T);
  const float* Vg  = (const float*)(ws + OFF_V);
  const float* Big = (const float*)(ws + OFF_BI);

  const int row0 = bx * 32;
  if (tid < 32) {
    sN[tid] = (row0 + tid < totF) ? idx[row0 + tid] : -1;
    // zero pad elements 700..703 of row tid (B1 is zero there; avoid NaN*0)
    int byte = (tid * 1408 + 1400) ^ ((tid & 7) << 4);
    *(unsigned long long*)((char*)As + byte) = 0ull;
  }
  __syncthreads();

  // stage x rows -> LDS bf16 (coalesced within rows; XOR-swizzled)
#pragma unroll 4
  for (int it = 0; it < 22; ++it) {
    int c = tid + it * 256;              // 32 rows x 175 f32x4 chunks = 5600
    if (c < 5600) {
      int r = c / 175, cc = c % 175;
      int node = sN[r];
      if (node >= 0) {
        f32x4 v = *(const f32x4*)(x + (size_t)node * 700 + cc * 4);
        svec4 p;
#pragma unroll
        for (int i = 0; i < 4; ++i) p[i] = f2bf(v[i]);
        int byte = (r * 1408 + cc * 8) ^ ((r & 7) << 4);
        *(svec4*)((char*)As + byte) = p;
      }
    }
  }

  const int wid = tid >> 6, lane = tid & 63;
  const int lr = lane & 15, gq = lane >> 4;

  float b1c[6], b2c[6];
#pragma unroll
  for (int n = 0; n < 6; ++n) {
    int col = (wid * 6 + n) * 16 + lr;
    b1c[n] = b1g[col];
    b2c[n] = Big[col];
  }
  __syncthreads();

  // ---------------- GEMM1: h1 = A @ W1g ----------------
  f32x4 acc[2][6] = {};
  for (int kt = 0; kt < K1T; ++kt) {
    Frag a[2];
#pragma unroll
    for (int m = 0; m < 2; ++m) {
      int row = m * 16 + lr;
      int byte = (row * 1408 + kt * 64 + gq * 16) ^ ((row & 7) << 4);
      a[m].v = *(const bf16x8*)((const char*)As + byte);
    }
#pragma unroll
    for (int n = 0; n < 6; ++n) {
      bf16x8 b = B1[((wid * 6 + n) * K1T + kt) * 64 + lane];
#pragma unroll
      for (int m = 0; m < 2; ++m)
        acc[m][n] = __builtin_amdgcn_mfma_f32_16x16x32_bf16(a[m].v, b, acc[m][n], 0, 0, 0);
    }
  }
  __syncthreads();   // all A reads complete before h1 overwrites the buffer

  // ---------------- h1 = elu(acc + b1g) -> LDS bf16 (swizzled) ----------------
#pragma unroll
  for (int m = 0; m < 2; ++m)
#pragma unroll
    for (int n = 0; n < 6; ++n) {
      int col = (wid * 6 + n) * 16 + lr;
#pragma unroll
      for (int r2 = 0; r2 < 4; ++r2) {
        int row = m * 16 + 4 * gq + r2;
        float hv = elu(acc[m][n][r2] + b1c[n]);
        int byte = (row * 768 + col * 2) ^ ((row & 15) << 4);
        *(short*)((char*)h1s + byte) = f2bf(hv);
      }
    }
  __syncthreads();

  // entity-branch per-node params
  int nde[2]; float nda[2];
#pragma unroll
  for (int m = 0; m < 2; ++m) {
    int node = sN[m * 16 + lr];
    if (node >= 0) { nde[m] = et[node]; nda[m] = ar[node]; }
    else           { nde[m] = 0;        nda[m] = 0.f; }
  }

  // ---------------- GEMM2: out = [h1|he] @ [W2g;W2e] ----------------
  f32x4 acc2[2][6] = {};
  for (int kt = 0; kt < K2T; ++kt) {
    Frag a[2];
    if (kt < 12) {
#pragma unroll
      for (int m = 0; m < 2; ++m) {
        int row = m * 16 + lr;
        int byte = (row * 768 + (kt * 32 + gq * 8) * 2) ^ ((row & 15) << 4);
        a[m].v = *(const bf16x8*)((const char*)h1s + byte);
      }
    } else {
      int c0 = (kt - 12) * 32 + gq * 8;
#pragma unroll
      for (int m = 0; m < 2; ++m) {
        const float* Tp = Tg + nde[m] * 384 + c0;
        const float* Vp = Vg + c0;
#pragma unroll
        for (int i = 0; i < 8; ++i)
          a[m].s[i] = f2bf(elu(Tp[i] + nda[m] * Vp[i]));
      }
    }
#pragma unroll
    for (int n = 0; n < 6; ++n) {
      bf16x8 b = B2[((wid * 6 + n) * K2T + kt) * 64 + lane];
#pragma unroll
      for (int m = 0; m < 2; ++m)
        acc2[m][n] = __builtin_amdgcn_mfma_f32_16x16x32_bf16(a[m].v, b, acc2[m][n], 0, 0, 0);
    }
  }

  // ---------------- epilogue: +bias2, scatter store (all rows are faces) ----------------
#pragma unroll
  for (int m = 0; m < 2; ++m) {
#pragma unroll
    for (int r2 = 0; r2 < 4; ++r2) {
      int node = sN[m * 16 + 4 * gq + r2];
      if (node >= 0) {
#pragma unroll
        for (int n = 0; n < 6; ++n) {
          int col = (wid * 6 + n) * 16 + lr;
          o[(size_t)node * HD + col] = acc2[m][n][r2] + b2c[n];
        }
      }
    }
  }
}

extern "C" void kernel_launch(void* const* d_in, const int* in_sizes, int n_in,
                              void* d_out, int out_size, void* d_ws, size_t ws_size,
                              hipStream_t stream) {
  (void)n_in; (void)out_size; (void)ws_size; (void)in_sizes;
  const float* x1  = (const float*)d_in[0];
  const float* is1 = (const float*)d_in[1];
  const int*   et1 = (const int*)d_in[2];
  const float* ar1 = (const float*)d_in[3];
  const float* x2  = (const float*)d_in[4];
  const float* is2 = (const float*)d_in[5];
  const int*   et2 = (const int*)d_in[6];
  const float* ar2 = (const float*)d_in[7];
  const float* W1g = (const float*)d_in[8];
  const float* b1g = (const float*)d_in[9];
  const float* W2g = (const float*)d_in[10];
  const float* b2g = (const float*)d_in[11];
  const float* W1e = (const float*)d_in[12];
  const float* b1e = (const float*)d_in[13];
  const float* W2e = (const float*)d_in[14];
  const float* b2e = (const float*)d_in[15];
  float* out = (float*)d_out;
  char* ws = (char*)d_ws;

  prep_kernel<<<dim3(288), dim3(256), 0, stream>>>(W1g, b1g, W2g, b2g, W1e, b1e, W2e, b2e, ws);
  count_kernel<<<dim3(NBLK, 2), dim3(1024), 0, stream>>>(is1, is2, ws);
  scan_kernel<<<dim3(1), dim3(64), 0, stream>>>(ws);
  compact_kernel<<<dim3(NBLK, 2), dim3(1024), 0, stream>>>(is1, is2, ws);

  dim3 grid(NN / 32 + 1, 2);    // worst case: ceil(F/32)+ceil((NN-F)/32) <= 3126
  face_embed_kernel<<<grid, dim3(256), 0, stream>>>(
      x1, et1, ar1, x2, et2, ar2, b1g, ws, out);
}

// Round 5
// 361.799 us; speedup vs baseline: 2.0880x; 1.0257x over previous
//
#include <hip/hip_runtime.h>
#include <hip/hip_bf16.h>

typedef __attribute__((ext_vector_type(8))) short short8;
typedef __attribute__((ext_vector_type(4))) short svec4;
typedef __attribute__((ext_vector_type(8))) __bf16 bf16x8;
typedef __attribute__((ext_vector_type(4))) float f32x4;

#define NN 100000
#define HD 384
#define K1T 22   // GEMM1 k-tiles: 704/32 (700 padded with zeros)
#define K2T 24   // GEMM2 k-tiles: 768/32 ([h1 | he])
#define NBLK 98  // ceil(NN/1024) for count/compact
#define HE_OFF 24576   // byte offset of he tile within shared buf

// d_ws byte offsets
#define OFF_B1  0         // W1g bf16 frag order: 24*22*64*8 shorts = 540672 B
#define OFF_B2  540672    // [W2g;W2e] bf16 frag order: 589824 B
#define OFF_T   1130496   // T[6][384] f32 = W1e[t]+b1e
#define OFF_V   1139712   // V[384] f32 = W1e[6]
#define OFF_BI  1141248   // bias2[384] f32 = b2g+b2e
#define OFF_IDX 1142784   // int idx[2][NN]: faces [0,totF), non-faces [totF,NN)
#define OFF_CNT 1942784   // int cnt[2][NBLK]
#define OFF_OFFS 1943568  // int offs[2][NBLK]
#define OFF_TOT 1944352   // int tot[2]

union Frag { short s[8]; bf16x8 v; };

__device__ __forceinline__ short f2bf(float f) {
  union { __bf16 h; short s; } u;
  u.h = (__bf16)f;
  return u.s;
}

__device__ __forceinline__ float elu(float v) {
  return v > 0.f ? v : __expf(v) - 1.f;
}

__global__ void prep_kernel(const float* __restrict__ W1g, const float* __restrict__ b1g,
                            const float* __restrict__ W2g, const float* __restrict__ b2g,
                            const float* __restrict__ W1e, const float* __restrict__ b1e,
                            const float* __restrict__ W2e, const float* __restrict__ b2e,
                            char* __restrict__ ws) {
  int t = blockIdx.x * 256 + threadIdx.x;
  short* B1 = (short*)(ws + OFF_B1);
  short* B2 = (short*)(ws + OFF_B2);
  float* Tt = (float*)(ws + OFF_T);
  float* Vt = (float*)(ws + OFF_V);
  float* Bi = (float*)(ws + OFF_BI);
  if (t < 33792) {                       // B1: (nt,kt,lane) -> 8 shorts
    int lane = t & 63, rest = t >> 6;
    int kt = rest % K1T, nt = rest / K1T;
    int col = nt * 16 + (lane & 15);
    int kb = kt * 32 + (lane >> 4) * 8;
    short8 v;
#pragma unroll
    for (int i = 0; i < 8; ++i) {
      int k = kb + i;
      v[i] = (k < 700) ? f2bf(W1g[k * 384 + col]) : (short)0;
    }
    *(short8*)(B1 + (size_t)t * 8) = v;
  } else if (t < 70656) {                // B2
    int t2 = t - 33792;
    int lane = t2 & 63, rest = t2 >> 6;
    int kt = rest % K2T, nt = rest / K2T;
    int col = nt * 16 + (lane & 15);
    int kb = kt * 32 + (lane >> 4) * 8;
    short8 v;
#pragma unroll
    for (int i = 0; i < 8; ++i) {
      int k = kb + i;
      v[i] = (k < 384) ? f2bf(W2g[k * 384 + col]) : f2bf(W2e[(k - 384) * 384 + col]);
    }
    *(short8*)(B2 + (size_t)t2 * 8) = v;
  } else if (t < 73728) {                // tables
    int r = t - 70656;
    int which = r / 384, c = r % 384;
    if (which < 6)       Tt[r] = W1e[which * 384 + c] + b1e[c];
    else if (which == 6) Vt[c] = W1e[6 * 384 + c];
    else                 Bi[c] = b2g[c] + b2e[c];
  }
}

__global__ void count_kernel(const float* __restrict__ isf1, const float* __restrict__ isf2,
                             char* __restrict__ ws) {
  int g = blockIdx.y;
  const float* isf = g ? isf2 : isf1;
  int i = blockIdx.x * 1024 + threadIdx.x;
  bool face = (i < NN) && (isf[i] > 0.5f);
  unsigned long long b = __ballot(face);
  __shared__ int wc[16];
  int lane = threadIdx.x & 63, wid = threadIdx.x >> 6;
  if (lane == 0) wc[wid] = __popcll(b);
  __syncthreads();
  if (threadIdx.x == 0) {
    int s = 0;
#pragma unroll
    for (int w = 0; w < 16; ++w) s += wc[w];
    ((int*)(ws + OFF_CNT))[g * NBLK + blockIdx.x] = s;
  }
}

__global__ void scan_kernel(char* __restrict__ ws) {
  int t = threadIdx.x;
  if (t < 2) {
    const int* cnt = (const int*)(ws + OFF_CNT) + t * NBLK;
    int* offs = (int*)(ws + OFF_OFFS) + t * NBLK;
    int* tot = (int*)(ws + OFF_TOT);
    int run = 0;
    for (int b = 0; b < NBLK; ++b) { offs[b] = run; run += cnt[b]; }
    tot[t] = run;
  }
}

__global__ void compact_kernel(const float* __restrict__ isf1, const float* __restrict__ isf2,
                               char* __restrict__ ws) {
  int g = blockIdx.y;
  const float* isf = g ? isf2 : isf1;
  const int* offs = (const int*)(ws + OFF_OFFS) + g * NBLK;
  int totF = ((const int*)(ws + OFF_TOT))[g];
  int* idx = (int*)(ws + OFF_IDX) + g * NN;
  int bx = blockIdx.x;
  int i = bx * 1024 + threadIdx.x;
  bool valid = i < NN;
  bool face = valid && (isf[i] > 0.5f);
  unsigned long long bf = __ballot(face);
  unsigned long long bv = __ballot(valid);
  int lane = threadIdx.x & 63, wid = threadIdx.x >> 6;
  __shared__ int wF[16], wV[16];
  if (lane == 0) { wF[wid] = __popcll(bf); wV[wid] = __popcll(bv); }
  __syncthreads();
  int baseF = 0, baseV = 0;
  for (int w = 0; w < wid; ++w) { baseF += wF[w]; baseV += wV[w]; }
  unsigned long long lmask = (1ull << lane) - 1ull;
  int pF = __popcll(bf & lmask);
  int pV = __popcll(bv & lmask);
  if (face) {
    idx[offs[bx] + baseF + pF] = i;
  } else if (valid) {
    int nfBefore = bx * 1024 - offs[bx];
    int nfIn = (baseV + pV) - (baseF + pF);
    idx[totF + nfBefore + nfIn] = i;
  }
}

// 32 gathered face rows/block, 4 waves (N-split): each wave 32r x 96c, acc[2][6].
// LDS: phase1 A-tile bf16 [32][704] swizzled (44 KB); phase2 h1 [32][384] (24 KB)
// + he [32][384] (24 KB) at HE_OFF. Total 49.3 KB -> 3 blocks/CU.
// B-frags ping-pong prefetched in registers (kt+=2, fully unrolled, static).
__global__ __launch_bounds__(256, 3) void face_embed_kernel(
    const float* __restrict__ x1, const int* __restrict__ et1, const float* __restrict__ ar1,
    const float* __restrict__ x2, const int* __restrict__ et2, const float* __restrict__ ar2,
    const float* __restrict__ b1g, const char* __restrict__ ws,
    float* __restrict__ out) {
  const int g = blockIdx.y;
  const float* x = g ? x2 : x1;
  const int* et  = g ? et2 : et1;
  const float* ar = g ? ar2 : ar1;
  float* o = out + (size_t)g * NN * HD;
  const int* idx = (const int*)(ws + OFF_IDX) + g * NN;
  const int totF = ((const int*)(ws + OFF_TOT))[g];
  const int nFB = (totF + 31) >> 5;
  const int bx = blockIdx.x;
  const int tid = threadIdx.x;

  if (bx >= nFB) {                       // ---- zero path (non-face rows) ----
    int totN = NN - totF;
    int base = (bx - nFB) * 32;
    if (base >= totN) return;
    const int* idxN = idx + totF;
    f32x4 z = {0.f, 0.f, 0.f, 0.f};
#pragma unroll
    for (int it = 0; it < 12; ++it) {
      int c = tid + it * 256;
      int r = c / 96, cc = c % 96;
      if (base + r < totN) {
        int node = idxN[base + r];
        *(f32x4*)(o + (size_t)node * HD + cc * 4) = z;
      }
    }
    return;
  }

  // ---- GEMM path on gathered face rows ----
  __shared__ char buf[49152];            // As [0,45056) phase1; h1 [0,24576)+he [24576,49152) phase2
  __shared__ int sN[32];
  char* As = buf;
  char* h1s = buf;

  const bf16x8* B1 = (const bf16x8*)(ws + OFF_B1);
  const bf16x8* B2 = (const bf16x8*)(ws + OFF_B2);
  const float* Tg  = (const float*)(ws + OFF_T);
  const float* Vg  = (const float*)(ws + OFF_V);
  const float* Big = (const float*)(ws + OFF_BI);

  const int row0 = bx * 32;
  if (tid < 32) {
    sN[tid] = (row0 + tid < totF) ? idx[row0 + tid] : -1;
    int byte = (tid * 1408 + 1400) ^ ((tid & 7) << 4);
    *(unsigned long long*)(As + byte) = 0ull;   // zero pad cols 700..703
  }
  __syncthreads();

  // stage x rows -> LDS bf16 (coalesced within rows; XOR-swizzled)
#pragma unroll 4
  for (int it = 0; it < 22; ++it) {
    int c = tid + it * 256;              // 32 rows x 175 f32x4 chunks = 5600
    if (c < 5600) {
      int r = c / 175, cc = c % 175;
      int node = sN[r];
      if (node >= 0) {
        f32x4 v = *(const f32x4*)(x + (size_t)node * 700 + cc * 4);
        svec4 p;
#pragma unroll
        for (int i = 0; i < 4; ++i) p[i] = f2bf(v[i]);
        int byte = (r * 1408 + cc * 8) ^ ((r & 7) << 4);
        *(svec4*)(As + byte) = p;
      }
    }
  }

  const int wid = tid >> 6, lane = tid & 63;
  const int lr = lane & 15, gq = lane >> 4;

  float b1c[6], b2c[6];
#pragma unroll
  for (int n = 0; n < 6; ++n) {
    int col = (wid * 6 + n) * 16 + lr;
    b1c[n] = b1g[col];
    b2c[n] = Big[col];
  }
  __syncthreads();

  // ---------------- GEMM1: h1 = A @ W1g (B ping-pong prefetch) ----------------
  f32x4 acc[2][6] = {};
  {
    Frag bP[6], bQ[6];
#pragma unroll
    for (int n = 0; n < 6; ++n) bP[n].v = B1[((wid * 6 + n) * K1T + 0) * 64 + lane];
#pragma unroll
    for (int kt = 0; kt < K1T; kt += 2) {
#pragma unroll
      for (int n = 0; n < 6; ++n) bQ[n].v = B1[((wid * 6 + n) * K1T + kt + 1) * 64 + lane];
      Frag a[2];
#pragma unroll
      for (int m = 0; m < 2; ++m) {
        int row = m * 16 + lr;
        int byte = (row * 1408 + kt * 64 + gq * 16) ^ ((row & 7) << 4);
        a[m].v = *(const bf16x8*)(As + byte);
      }
#pragma unroll
      for (int n = 0; n < 6; ++n)
#pragma unroll
        for (int m = 0; m < 2; ++m)
          acc[m][n] = __builtin_amdgcn_mfma_f32_16x16x32_bf16(a[m].v, bP[n].v, acc[m][n], 0, 0, 0);
      if (kt + 2 < K1T) {
#pragma unroll
        for (int n = 0; n < 6; ++n) bP[n].v = B1[((wid * 6 + n) * K1T + kt + 2) * 64 + lane];
      }
#pragma unroll
      for (int m = 0; m < 2; ++m) {
        int row = m * 16 + lr;
        int byte = (row * 1408 + (kt + 1) * 64 + gq * 16) ^ ((row & 7) << 4);
        a[m].v = *(const bf16x8*)(As + byte);
      }
#pragma unroll
      for (int n = 0; n < 6; ++n)
#pragma unroll
        for (int m = 0; m < 2; ++m)
          acc[m][n] = __builtin_amdgcn_mfma_f32_16x16x32_bf16(a[m].v, bQ[n].v, acc[m][n], 0, 0, 0);
    }
  }
  __syncthreads();   // all A reads complete before h1/he overwrite the buffer

  // ---------------- h1 = elu(acc + b1g) -> LDS; he computed once -> LDS ----------------
#pragma unroll
  for (int m = 0; m < 2; ++m)
#pragma unroll
    for (int n = 0; n < 6; ++n) {
      int col = (wid * 6 + n) * 16 + lr;
#pragma unroll
      for (int r2 = 0; r2 < 4; ++r2) {
        int row = m * 16 + 4 * gq + r2;
        float hv = elu(acc[m][n][r2] + b1c[n]);
        int byte = (row * 768 + col * 2) ^ ((row & 15) << 4);
        *(short*)(h1s + byte) = f2bf(hv);
      }
    }
  // he[row][c] = elu(T[et[row]][c] + area[row]*V[c]), cooperative (8 thr/row x 48 cols)
  {
    int row = tid >> 3;
    int c0 = (tid & 7) * 48;
    int node = sN[row];
    int e = 0; float arv = 0.f;
    if (node >= 0) { e = et[node]; arv = ar[node]; }
    const float* Tp = Tg + e * 384 + c0;
    const float* Vp = Vg + c0;
#pragma unroll
    for (int j = 0; j < 48; j += 2) {
      unsigned lo = (unsigned short)f2bf(elu(Tp[j] + arv * Vp[j]));
      unsigned hi = (unsigned short)f2bf(elu(Tp[j + 1] + arv * Vp[j + 1]));
      int byte = HE_OFF + ((row * 768 + (c0 + j) * 2) ^ ((row & 15) << 4));
      *(unsigned*)(buf + byte) = lo | (hi << 16);
    }
  }
  __syncthreads();

  // ---------------- GEMM2: out = [h1|he] @ [W2g;W2e] (uniform LDS A, B ping-pong) ----------------
  f32x4 acc2[2][6] = {};
  {
    Frag bP[6], bQ[6];
#pragma unroll
    for (int n = 0; n < 6; ++n) bP[n].v = B2[((wid * 6 + n) * K2T + 0) * 64 + lane];
#pragma unroll
    for (int kt = 0; kt < K2T; kt += 2) {
#pragma unroll
      for (int n = 0; n < 6; ++n) bQ[n].v = B2[((wid * 6 + n) * K2T + kt + 1) * 64 + lane];
      Frag a[2];
#pragma unroll
      for (int m = 0; m < 2; ++m) {
        int row = m * 16 + lr;
        int kk = kt < 12 ? kt : kt - 12;
        int base = kt < 12 ? 0 : HE_OFF;
        int byte = base + ((row * 768 + kk * 64 + gq * 16) ^ ((row & 15) << 4));
        a[m].v = *(const bf16x8*)(buf + byte);
      }
#pragma unroll
      for (int n = 0; n < 6; ++n)
#pragma unroll
        for (int m = 0; m < 2; ++m)
          acc2[m][n] = __builtin_amdgcn_mfma_f32_16x16x32_bf16(a[m].v, bP[n].v, acc2[m][n], 0, 0, 0);
      if (kt + 2 < K2T) {
#pragma unroll
        for (int n = 0; n < 6; ++n) bP[n].v = B2[((wid * 6 + n) * K2T + kt + 2) * 64 + lane];
      }
#pragma unroll
      for (int m = 0; m < 2; ++m) {
        int row = m * 16 + lr;
        int kt1 = kt + 1;
        int kk = kt1 < 12 ? kt1 : kt1 - 12;
        int base = kt1 < 12 ? 0 : HE_OFF;
        int byte = base + ((row * 768 + kk * 64 + gq * 16) ^ ((row & 15) << 4));
        a[m].v = *(const bf16x8*)(buf + byte);
      }
#pragma unroll
      for (int n = 0; n < 6; ++n)
#pragma unroll
        for (int m = 0; m < 2; ++m)
          acc2[m][n] = __builtin_amdgcn_mfma_f32_16x16x32_bf16(a[m].v, bQ[n].v, acc2[m][n], 0, 0, 0);
    }
  }

  // ---------------- epilogue: +bias2, scatter store (all rows are faces) ----------------
#pragma unroll
  for (int m = 0; m < 2; ++m) {
#pragma unroll
    for (int r2 = 0; r2 < 4; ++r2) {
      int node = sN[m * 16 + 4 * gq + r2];
      if (node >= 0) {
#pragma unroll
        for (int n = 0; n < 6; ++n) {
          int col = (wid * 6 + n) * 16 + lr;
          o[(size_t)node * HD + col] = acc2[m][n][r2] + b2c[n];
        }
      }
    }
  }
}

extern "C" void kernel_launch(void* const* d_in, const int* in_sizes, int n_in,
                              void* d_out, int out_size, void* d_ws, size_t ws_size,
                              hipStream_t stream) {
  (void)n_in; (void)out_size; (void)ws_size; (void)in_sizes;
  const float* x1  = (const float*)d_in[0];
  const float* is1 = (const float*)d_in[1];
  const int*   et1 = (const int*)d_in[2];
  const float* ar1 = (const float*)d_in[3];
  const float* x2  = (const float*)d_in[4];
  const float* is2 = (const float*)d_in[5];
  const int*   et2 = (const int*)d_in[6];
  const float* ar2 = (const float*)d_in[7];
  const float* W1g = (const float*)d_in[8];
  const float* b1g = (const float*)d_in[9];
  const float* W2g = (const float*)d_in[10];
  const float* b2g = (const float*)d_in[11];
  const float* W1e = (const float*)d_in[12];
  const float* b1e = (const float*)d_in[13];
  const float* W2e = (const float*)d_in[14];
  const float* b2e = (const float*)d_in[15];
  float* out = (float*)d_out;
  char* ws = (char*)d_ws;

  prep_kernel<<<dim3(288), dim3(256), 0, stream>>>(W1g, b1g, W2g, b2g, W1e, b1e, W2e, b2e, ws);
  count_kernel<<<dim3(NBLK, 2), dim3(1024), 0, stream>>>(is1, is2, ws);
  scan_kernel<<<dim3(1), dim3(64), 0, stream>>>(ws);
  compact_kernel<<<dim3(NBLK, 2), dim3(1024), 0, stream>>>(is1, is2, ws);

  dim3 grid(NN / 32 + 1, 2);
  face_embed_kernel<<<grid, dim3(256), 0, stream>>>(
      x1, et1, ar1, x2, et2, ar2, b1g, ws, out);
}